// Round 11
// baseline (1745.292 us; speedup 1.0000x reference)
//
#include <hip/hip_runtime.h>

#define Bz 32
#define Tz 256
#define Ez 256
#define Hz 256
#define Kz 48
#define G4 1024   // 4*H
#define H2 512    // 2*H

typedef __attribute__((ext_vector_type(8))) short short8;
typedef __attribute__((ext_vector_type(4))) float f32x4;
typedef unsigned short ushort_t;
typedef unsigned int uint_t;
typedef unsigned long long ull_t;
typedef __attribute__((ext_vector_type(4))) uint_t uint4_t;

__device__ __forceinline__ float bf2f(ushort_t u) {
    unsigned int x = ((unsigned int)u) << 16;
    union { unsigned int i; float f; } c; c.i = x; return c.f;
}
__device__ __forceinline__ ushort_t f2bf(float f) {
    union { float f; unsigned int i; } c; c.f = f;
    unsigned int x = c.i;
    unsigned int lsb = (x >> 16) & 1u;
    x += 0x7fffu + lsb;
    return (ushort_t)(x >> 16);
}
__device__ __forceinline__ float sigm(float x) { return 1.f / (1.f + __expf(-x)); }
__device__ __forceinline__ float tanh_f(float x) { return 1.f - 2.f / (__expf(2.f * x) + 1.f); }

#define MFMA16(a, b, c) __builtin_amdgcn_mfma_f32_16x16x32_bf16((a), (b), (c), 0, 0, 0)

// Per-wave fragment poll: lane l reads its 8 MFMA a-frags (16B each) from the
// RELAYOUTED hbuf (word [tile][k][l][j] at tile*1024 + k*128 + l*2 + j), so a
// wave's loads are 1024B-contiguous per instruction. IC path (sc0 sc1), ONE
// vmcnt(0) per sweep (R10-proven batching). Two bases: k=0..3 / k=4..7
// (offset k*1024B; 13-bit signed imm caps at 4095).
__device__ __forceinline__ void pollfrag8(const ull_t* p0, const ull_t* p1, uint4_t* o)
{
    asm volatile(
        "global_load_dwordx4 %0, %8, off sc0 sc1\n\t"
        "global_load_dwordx4 %1, %8, off offset:1024 sc0 sc1\n\t"
        "global_load_dwordx4 %2, %8, off offset:2048 sc0 sc1\n\t"
        "global_load_dwordx4 %3, %8, off offset:3072 sc0 sc1\n\t"
        "global_load_dwordx4 %4, %9, off sc0 sc1\n\t"
        "global_load_dwordx4 %5, %9, off offset:1024 sc0 sc1\n\t"
        "global_load_dwordx4 %6, %9, off offset:2048 sc0 sc1\n\t"
        "global_load_dwordx4 %7, %9, off offset:3072 sc0 sc1\n\t"
        "s_waitcnt vmcnt(0)"
        : "=&v"(o[0]), "=&v"(o[1]), "=&v"(o[2]), "=&v"(o[3]),
          "=&v"(o[4]), "=&v"(o[5]), "=&v"(o[6]), "=&v"(o[7])
        : "v"(p0), "v"(p1)
        : "memory");
}

// ---------------- fp32 -> bf16 weight conversion, all 9 matrices in one dispatch ----------------
struct CvtArgs {
    const float* s[9];
    ushort_t* d[9];
    int n[9];
};
__global__ __launch_bounds__(256) void cvt_all(CvtArgs a)
{
    int y = blockIdx.y;
    const float* src = a.s[y];
    ushort_t* dst = a.d[y];
    int n = a.n[y];
    int i = (blockIdx.x * 256 + threadIdx.x) * 4;
    if (i < n) {
        float4 v = *(const float4*)(src + i);
        ushort_t o[4] = { f2bf(v.x), f2bf(v.y), f2bf(v.z), f2bf(v.w) };
        *(uint2*)(dst + i) = *(uint2*)o;
    }
}

// ---------------- embedding gather (fp32 -> bf16) + mask output ----------------
__global__ __launch_bounds__(64) void embed_kernel(
    const int* __restrict__ sent, const float* __restrict__ embed,
    ushort_t* __restrict__ emb, float* __restrict__ mask_out)
{
    int blk = blockIdx.x;             // b*T + t
    int b = blk >> 8, t = blk & 255;
    int s = sent[blk];
    int tid = threadIdx.x;            // 64 threads x 4 elems
    float4 v = *(const float4*)(embed + (size_t)s * Ez + tid * 4);
    ushort_t o[4] = { f2bf(v.x), f2bf(v.y), f2bf(v.z), f2bf(v.w) };
    *(uint2*)(emb + ((size_t)t * Bz + b) * Ez + tid * 4) = *(uint2*)o;
    if (tid == 0) mask_out[blk] = (s != 0) ? 1.0f : 0.0f;
}

// ---------------- input-projection GEMM (R7-proven m97 structure, kept) ----------------
__global__ __launch_bounds__(256) void gemm_xproj(
    const ushort_t* __restrict__ A,                                      // (M, Kd) bf16
    const ushort_t* __restrict__ Wf, const ushort_t* __restrict__ Wb,    // (1024, Kd) bf16
    const float* __restrict__ biasf, const float* __restrict__ biasb,    // (1024,) fp32
    ushort_t* __restrict__ Cf, ushort_t* __restrict__ Cb,                // (M, 1024) bf16
    int M, int Kd)
{
    const ushort_t* W = blockIdx.z ? Wb : Wf;
    const float* bias = blockIdx.z ? biasb : biasf;
    ushort_t* C = blockIdx.z ? Cb : Cf;
    __shared__ __attribute__((aligned(16))) ushort_t sA[128 * 32];   // 8KB, row-major [128][32]
    __shared__ __attribute__((aligned(16))) ushort_t sB[128 * 32];   // 8KB

    int m0 = blockIdx.x * 128, n0 = blockIdx.y * 128;
    int tid = threadIdx.x, l = tid & 63, w = tid >> 6;
    int lr = l & 15, lq = l >> 4;
    int mw = (w & 1) * 64, nw = (w >> 1) * 64;     // wave's 64x64 quadrant

    int srow_lane = l >> 2;
    int scol_lane = (l & 3) * 8;

    f32x4 acc[4][4] = {};
    for (int ko = 0; ko < Kd; ko += 32) {
        #pragma unroll
        for (int j = 0; j < 4; j++) {
            int seg = w * 4 + j;
            const ushort_t* src;
            ushort_t* dst;
            if (seg < 8) {
                src = A + (size_t)(m0 + seg * 16 + srow_lane) * Kd + ko + scol_lane;
                dst = sA + seg * 512;
            } else {
                src = W + (size_t)(n0 + (seg - 8) * 16 + srow_lane) * Kd + ko + scol_lane;
                dst = sB + (seg - 8) * 512;
            }
            __builtin_amdgcn_global_load_lds(src, dst, 16, 0, 0);
        }
        asm volatile("s_waitcnt vmcnt(0)" ::: "memory");
        __syncthreads();

        short8 af[4], bf_[4];
        #pragma unroll
        for (int mt = 0; mt < 4; mt++)
            af[mt] = *(const short8*)(&sA[(mw + mt * 16 + lr) * 32 + lq * 8]);
        #pragma unroll
        for (int nt = 0; nt < 4; nt++)
            bf_[nt] = *(const short8*)(&sB[(nw + nt * 16 + lr) * 32 + lq * 8]);
        #pragma unroll
        for (int mt = 0; mt < 4; mt++)
            #pragma unroll
            for (int nt = 0; nt < 4; nt++)
                acc[mt][nt] = MFMA16(af[mt], bf_[nt], acc[mt][nt]);
        __syncthreads();
    }

    #pragma unroll
    for (int mt = 0; mt < 4; mt++)
        #pragma unroll
        for (int nt = 0; nt < 4; nt++)
            #pragma unroll
            for (int r = 0; r < 4; r++) {
                int row = m0 + mw + mt * 16 + lq * 4 + r;
                int col = n0 + nw + nt * 16 + lr;
                float v = acc[mt][nt][r] + bias[col];
                C[(size_t)row * G4 + col] = f2bf(v);
            }
}

// ---------------- LSTM recurrence, one layer, both dirs ----------------
// 32 blocks x 256 threads. R10's batched IC sweep kept; THIS ROUND removes
// the sH staging + block-wide barrier by polling MFMA fragments DIRECTLY
// into registers, enabled by a fragment-major hbuf RELAYOUT:
//   word [tile][k][lane][j] at  tile*1024 + k*128 + l*2 + j
//   (tile = batch>>4, lane = (batch&15) + lq*16, k = unit-slice, j = word-in-frag)
// Consumer: lane l of wave w (tile=w&1) polls its 8 frags at
//   base = tile*1024 + l*2, offsets k*1024B -> 1024B-contiguous per wave
//   per instruction (R5's coalescing failure fixed by the relayout).
// Publisher: wave's 32 upd lanes cover one contiguous 256B run.
// Detection is per-WAVE (own tile only), no __syncthreads, no LDS staging.
// Overwrite safety per wave-parity class: even waves publish AND consume
// tile0 (odd: tile1); publish(s+1) requires own detect(s), transitively all
// class peers' detect(s-1) -> buffer (s+1)&1's step-s-1 readers are done.
// tau(s) != tau(s-2) (4-phase tag) kills ABA. Tag = bit14 of each 8B word.
#define HWRD 2048       // words per buffer: B*H/4

__global__ __launch_bounds__(256, 1) void lstm_layer(
    const ushort_t* __restrict__ Whh_f, const ushort_t* __restrict__ Whh_b,  // (1024,256) bf16
    const ushort_t* __restrict__ Xp_f, const ushort_t* __restrict__ Xp_b,    // (T*B, 1024) preact incl bias
    const int* __restrict__ lengths,                                         // (B,)
    ushort_t* __restrict__ hcat,                                             // (T*B, 512)
    ull_t* __restrict__ hbuf)       // [buf(2)][dir(2)][2048] fragment-major words, pre-zeroed
{
    __shared__ float sG[4][16][34];   // per-wave gates scratch (stride 34: <=2-way)

    int bid = blockIdx.x;
    int dir = bid >> 4;
    int sub = bid & 15;
    int h0 = sub * 16;
    const ushort_t* Whh = dir ? Whh_b : Whh_f;
    const ushort_t* Xp  = dir ? Xp_b  : Xp_f;
    int tid = threadIdx.x, l = tid & 63, w = tid >> 6;
    int lr = l & 15, lq = l >> 4;
    int mw = (w & 1) * 16;       // batch tile (== my poll tile)
    int P  = w >> 1;             // unit pair
    int U0w = h0 + P * 8;

    // B fragments in registers; col cI=lr -> (unit U0w + (lr>>2), gate lr&3), tile1 = +4 units
    short8 bw0[8], bw1[8];
    int gA = (lr & 3) * Hz + U0w + (lr >> 2);   // Whh row == Xp col, tile 0
    int gB = gA + 4;                             // tile 1
    {
        const ushort_t* W0 = Whh + (size_t)gA * Hz;
        const ushort_t* W1 = Whh + (size_t)gB * Hz;
        #pragma unroll
        for (int k = 0; k < 8; k++) {
            bw0[k] = *(const short8*)(W0 + k * 32 + lq * 8);
            bw1[k] = *(const short8*)(W1 + k * 32 + lq * 8);
        }
    }

    // update lanes: l<32: b_loc = l&15, q = (l>>4)&1 -> units U0w + q*4 .. +4
    int upd = (l < 32);
    int bloc = l & 15;
    int q = (l >> 4) & 1;
    int batch = mw + bloc;
    int lenb = lengths[batch];
    float c4[4] = {0.f, 0.f, 0.f, 0.f};
    ull_t prevw = 0;                               // last published word (untagged)
    int g = sub * 4 + P * 2 + q;                   // my unit-quad index 0..63
    int pubw = (batch >> 4) * 1024 + (g >> 3) * 128
             + (batch & 15) * 2 + ((g >> 1) & 3) * 32 + (g & 1);  // fragment-major
    int hcoff = dir * Hz + U0w + q * 4;            // hcat ushort offset within row
    int fbase = (w & 1) * 1024 + l * 2;            // my fragment base word

    for (int s = 0; s < Tz; s++) {
        int t_act = dir ? (Tz - 1 - s) : s;
        const ushort_t* Xrow = Xp + (size_t)t_act * Bz * G4;

        // Xp prefetch (independent of h; overlaps the poll)
        float xv0[4], xv1[4];
        #pragma unroll
        for (int r = 0; r < 4; r++) {
            int brow = mw + lq * 4 + r;
            xv0[r] = bf2f(Xrow[(size_t)brow * G4 + gA]);
            xv1[r] = bf2f(Xrow[(size_t)brow * G4 + gB]);
        }

        // ---- per-wave fragment poll: 8 x dwordx4, one vmcnt(0)/sweep ----
        const ull_t* hcur = hbuf + ((s & 1) * 2 + dir) * HWRD;
        const ull_t* p0 = hcur + fbase;            // k=0..3 (offsets 0..3072B)
        const ull_t* p1 = p0 + 512;                // k=4..7
        uint_t tagc = (uint_t)(((s >> 1) ^ s) & 1);
        uint4_t fr[8];
        for (;;) {
            pollfrag8(p0, p1, fr);
            uint_t ok = 1u;
            #pragma unroll
            for (int k = 0; k < 8; k++)
                ok &= (((fr[k].x >> 14) & 1u) == tagc) &
                      (((fr[k].z >> 14) & 1u) == tagc);
            if (ok) break;
        }
        #pragma unroll
        for (int k = 0; k < 8; k++) { fr[k].x &= ~0x4000u; fr[k].z &= ~0x4000u; }

        // ---- 16 MFMAs (A straight from polled regs, B resident) ----
        f32x4 acc0 = {}, acc1 = {};
        #pragma unroll
        for (int k = 0; k < 8; k++) {
            short8 a;
            __builtin_memcpy(&a, &fr[k], 16);
            acc0 = MFMA16(a, bw0[k], acc0);
            acc1 = MFMA16(a, bw1[k], acc1);
        }
        // gates + Xp -> per-wave LDS transpose
        #pragma unroll
        for (int r = 0; r < 4; r++) {
            sG[w][lq * 4 + r][lr]      = acc0[r] + xv0[r];
            sG[w][lq * 4 + r][16 + lr] = acc1[r] + xv1[r];
        }
        asm volatile("s_waitcnt lgkmcnt(0)" ::: "memory");   // wave-local ordering

        // ---- cell update + tagged publish (lanes 0..31 of each wave) ----
        uint_t tagp = (uint_t)((((s + 1) >> 1) ^ (s + 1)) & 1);
        if (upd) {
            int msk = (t_act < lenb);
            ushort_t hx[4], hc[4];
            const ushort_t* ho = (const ushort_t*)&prevw;
            #pragma unroll
            for (int j = 0; j < 4; j++) {
                int cb = q * 16 + j * 4;
                float gi = sG[w][bloc][cb], gf = sG[w][bloc][cb + 1];
                float gg = sG[w][bloc][cb + 2], go = sG[w][bloc][cb + 3];
                float c2 = sigm(gf) * c4[j] + sigm(gi) * tanh_f(gg);
                float h2 = sigm(go) * tanh_f(c2);
                if (msk) c4[j] = c2;
                ushort_t hn = f2bf(h2);
                hx[j] = msk ? hn : ho[j];
                hc[j] = msk ? hn : (ushort_t)0;
            }
            ull_t wd; __builtin_memcpy(&wd, hx, 8);
            prevw = wd;
            wd |= ((ull_t)tagp) << 14;
            ull_t* hnxt = hbuf + (((s + 1) & 1) * 2 + dir) * HWRD;
            __hip_atomic_store(&hnxt[pubw], wd,
                               __ATOMIC_RELAXED, __HIP_MEMORY_SCOPE_AGENT);
            ull_t wc; __builtin_memcpy(&wc, hc, 8);
            *(ull_t*)(hcat + ((size_t)t_act * Bz + batch) * H2 + hcoff) = wc;
        }
    }
}

// ---------------- emit GEMM: (8192,512) @ Wout(48,512)^T + bout -> fp32 out[b][t][k] ----------------
__global__ __launch_bounds__(256) void gemm_emit(
    const ushort_t* __restrict__ A, const ushort_t* __restrict__ Wout,
    const float* __restrict__ bout, float* __restrict__ emit_out)
{
    int tid = threadIdx.x, l = tid & 63, w = tid >> 6;
    int m0 = blockIdx.x * 64 + w * 16;
    int lr = l & 15, lq = l >> 4;
    f32x4 acc[3] = {};
    for (int ko = 0; ko < H2; ko += 32) {
        short8 a = *(const short8*)(A + (size_t)(m0 + lr) * H2 + ko + lq * 8);
        #pragma unroll
        for (int nt = 0; nt < 3; nt++) {
            short8 bfr = *(const short8*)(Wout + (size_t)(nt * 16 + lr) * H2 + ko + lq * 8);
            acc[nt] = MFMA16(a, bfr, acc[nt]);
        }
    }
    #pragma unroll
    for (int nt = 0; nt < 3; nt++)
        #pragma unroll
        for (int r = 0; r < 4; r++) {
            int row = m0 + lq * 4 + r;            // t*B + b
            int col = nt * 16 + lr;
            float v = acc[nt][r] + bout[col];
            int t = row >> 5, b = row & 31;
            emit_out[((size_t)b * Tz + t) * Kz + col] = v;
        }
}

// ---------------- CRF numerator (reads emit from out, [b][t][k] fp32) ----------------
__global__ __launch_bounds__(256) void crf_num(
    const float* __restrict__ emit, const int* __restrict__ sent,
    const int* __restrict__ tags, const int* __restrict__ lengths,
    const float* __restrict__ trans, const float* __restrict__ start_t,
    const float* __restrict__ end_t, float* __restrict__ num)
{
    __shared__ float red[4];
    int b = blockIdx.x, t = threadIdx.x;
    int tg = tags[b * Tz + t];
    float term;
    if (t == 0) {
        term = start_t[tg] + emit[(size_t)b * Tz * Kz + tg];
        int len = lengths[b];
        term += end_t[tags[b * Tz + len - 1]];
    } else if (sent[b * Tz + t] != 0) {
        int tp = tags[b * Tz + t - 1];
        term = trans[tp * Kz + tg] + emit[((size_t)b * Tz + t) * Kz + tg];
    } else term = 0.f;
    #pragma unroll
    for (int off = 1; off < 64; off <<= 1) term += __shfl_xor(term, off);
    int w = t >> 6;
    if ((t & 63) == 0) red[w] = term;
    __syncthreads();
    if (t == 0) num[b] = red[0] + red[1] + red[2] + red[3];
}

// ---------------- CRF denominator (forward algorithm), one wave per batch ----------------
__global__ __launch_bounds__(64) void crf_den(
    const float* __restrict__ emit, const int* __restrict__ lengths,
    const float* __restrict__ trans, const float* __restrict__ start_t,
    const float* __restrict__ end_t, float* __restrict__ den)
{
    __shared__ float sT[Kz * Kz];     // [i*48 + l]
    __shared__ float sS[Kz];
    int b = blockIdx.x, l = threadIdx.x;
    for (int i = l; i < Kz * Kz; i += 64) sT[i] = trans[i];
    int len = lengths[b];
    bool act = l < Kz;
    float s = act ? (start_t[l] + emit[(size_t)b * Tz * Kz + l]) : -1e30f;
    for (int t = 1; t < len; t++) {
        float em = act ? emit[((size_t)b * Tz + t) * Kz + l] : 0.f;
        if (act) sS[l] = s;
        float M = s;
        #pragma unroll
        for (int off = 1; off < 64; off <<= 1) M = fmaxf(M, __shfl_xor(M, off));
        float a0 = 0.f, a1 = 0.f, a2 = 0.f, a3 = 0.f;
        #pragma unroll 4
        for (int i = 0; i < Kz; i += 4) {
            a0 += __expf(sS[i]     + sT[i * Kz + l]       - M);
            a1 += __expf(sS[i + 1] + sT[(i + 1) * Kz + l] - M);
            a2 += __expf(sS[i + 2] + sT[(i + 2) * Kz + l] - M);
            a3 += __expf(sS[i + 3] + sT[(i + 3) * Kz + l] - M);
        }
        float sum = (a0 + a1) + (a2 + a3);
        if (act) s = em + M + __logf(sum);
    }
    float v = act ? (s + end_t[l]) : -1e30f;
    float M = v;
    #pragma unroll
    for (int off = 1; off < 64; off <<= 1) M = fmaxf(M, __shfl_xor(M, off));
    float accv = act ? __expf(v - M) : 0.f;
    #pragma unroll
    for (int off = 1; off < 64; off <<= 1) accv += __shfl_xor(accv, off);
    if (l == 0) den[b] = M + __logf(accv);
}

// ---------------- final loss ----------------
__global__ __launch_bounds__(64) void crf_loss(
    const float* __restrict__ num, const float* __restrict__ den, float* __restrict__ out)
{
    int l = threadIdx.x;
    float v = (l < Bz) ? (num[l] - den[l]) : 0.f;
    #pragma unroll
    for (int off = 1; off < 64; off <<= 1) v += __shfl_xor(v, off);
    if (l == 0) out[0] = v / (float)Bz;
}

extern "C" void kernel_launch(void* const* d_in, const int* in_sizes, int n_in,
                              void* d_out, int out_size, void* d_ws, size_t ws_size,
                              hipStream_t stream) {
    const int* sent      = (const int*)d_in[0];
    const int* lengths   = (const int*)d_in[1];
    const int* tags      = (const int*)d_in[2];
    const float* embed   = (const float*)d_in[3];
    const float* Wih0f = (const float*)d_in[4];
    const float* Whh0f = (const float*)d_in[5];
    const float* b0f   = (const float*)d_in[6];
    const float* Wih0b = (const float*)d_in[7];
    const float* Whh0b = (const float*)d_in[8];
    const float* b0b   = (const float*)d_in[9];
    const float* Wih1f = (const float*)d_in[10];
    const float* Whh1f = (const float*)d_in[11];
    const float* b1f   = (const float*)d_in[12];
    const float* Wih1b = (const float*)d_in[13];
    const float* Whh1b = (const float*)d_in[14];
    const float* b1b   = (const float*)d_in[15];
    const float* Wout  = (const float*)d_in[16];
    const float* bout  = (const float*)d_in[17];
    const float* start_t = (const float*)d_in[18];
    const float* end_t   = (const float*)d_in[19];
    const float* trans   = (const float*)d_in[20];

    char* ws = (char*)d_ws;
    ushort_t* Xp_f  = (ushort_t*)(ws);                        // 16 MB
    ushort_t* Xp_b  = (ushort_t*)(ws + 16777216);             // 16 MB
    ushort_t* hcat  = (ushort_t*)(ws + 33554432);             // 8 MB (layer0 out, then layer1 out)
    ushort_t* emb   = (ushort_t*)(ws + 41943040);             // 4 MB
    ushort_t* Whh0f_c = (ushort_t*)(ws + 46137344);           // 512 KB each
    ushort_t* Whh0b_c = (ushort_t*)(ws + 46661632);
    ushort_t* Wih0f_c = (ushort_t*)(ws + 47185920);
    ushort_t* Wih0b_c = (ushort_t*)(ws + 47710208);
    ushort_t* Wih1f_c = (ushort_t*)(ws + 48234496);           // 1 MB each
    ushort_t* Wih1b_c = (ushort_t*)(ws + 49283072);
    ushort_t* Whh1f_c = (ushort_t*)(ws + 50331648);           // 512 KB each
    ushort_t* Whh1b_c = (ushort_t*)(ws + 50855936);
    ushort_t* Wout_c  = (ushort_t*)(ws + 51380224);           // 48 KB
    ull_t*    hbufL0 = (ull_t*)(ws + 51429376);               // 128 KB: [2][2][2048] 8B words
    ull_t*    hbufL1 = (ull_t*)(ws + 51560448);               // 128 KB
    float*    num   = (float*)   (ws + 51691520);
    float*    den   = (float*)   (ws + 51691776);

    float* out      = (float*)d_out;                          // emit [B][T][K]
    float* loss_out = out + (size_t)Bz * Tz * Kz;             // 393216
    float* mask_out = loss_out + 1;                           // (B,T)

    // zero both layers' h double-buffers (tag protocol: zero word = valid h=0 for step 0)
    hipMemsetAsync(hbufL0, 0, 262144, stream);

    CvtArgs ca;
    ca.s[0] = Whh0f; ca.d[0] = Whh0f_c; ca.n[0] = 262144;
    ca.s[1] = Whh0b; ca.d[1] = Whh0b_c; ca.n[1] = 262144;
    ca.s[2] = Wih0f; ca.d[2] = Wih0f_c; ca.n[2] = 262144;
    ca.s[3] = Wih0b; ca.d[3] = Wih0b_c; ca.n[3] = 262144;
    ca.s[4] = Wih1f; ca.d[4] = Wih1f_c; ca.n[4] = 524288;
    ca.s[5] = Wih1b; ca.d[5] = Wih1b_c; ca.n[5] = 524288;
    ca.s[6] = Whh1f; ca.d[6] = Whh1f_c; ca.n[6] = 262144;
    ca.s[7] = Whh1b; ca.d[7] = Whh1b_c; ca.n[7] = 262144;
    ca.s[8] = Wout;  ca.d[8] = Wout_c;  ca.n[8] = 24576;
    cvt_all<<<dim3(512, 9), 256, 0, stream>>>(ca);

    embed_kernel<<<Bz * Tz, 64, 0, stream>>>(sent, embed, emb, mask_out);

    gemm_xproj<<<dim3(Tz * Bz / 128, G4 / 128, 2), 256, 0, stream>>>(
        emb, Wih0f_c, Wih0b_c, b0f, b0b, Xp_f, Xp_b, Tz * Bz, Ez);

    lstm_layer<<<32, 256, 0, stream>>>(Whh0f_c, Whh0b_c, Xp_f, Xp_b, lengths, hcat, hbufL0);

    gemm_xproj<<<dim3(Tz * Bz / 128, G4 / 128, 2), 256, 0, stream>>>(
        hcat, Wih1f_c, Wih1b_c, b1f, b1b, Xp_f, Xp_b, Tz * Bz, H2);

    lstm_layer<<<32, 256, 0, stream>>>(Whh1f_c, Whh1b_c, Xp_f, Xp_b, lengths, hcat, hbufL1);

    gemm_emit<<<Tz * Bz / 64, 256, 0, stream>>>(hcat, Wout_c, bout, out);

    crf_num<<<Bz, 256, 0, stream>>>(out, sent, tags, lengths, trans, start_t, end_t, num);
    crf_den<<<Bz, 64, 0, stream>>>(out, lengths, trans, start_t, end_t, den);
    crf_loss<<<1, 64, 0, stream>>>(num, den, loss_out);
}

// Round 12
// 1627.080 us; speedup vs baseline: 1.0727x; 1.0727x over previous
//
#include <hip/hip_runtime.h>

#define Bz 32
#define Tz 256
#define Ez 256
#define Hz 256
#define Kz 48
#define G4 1024   // 4*H
#define H2 512    // 2*H

typedef __attribute__((ext_vector_type(8))) short short8;
typedef __attribute__((ext_vector_type(4))) float f32x4;
typedef unsigned short ushort_t;
typedef unsigned int uint_t;
typedef unsigned long long ull_t;

__device__ __forceinline__ float bf2f(ushort_t u) {
    unsigned int x = ((unsigned int)u) << 16;
    union { unsigned int i; float f; } c; c.i = x; return c.f;
}
__device__ __forceinline__ ushort_t f2bf(float f) {
    union { float f; unsigned int i; } c; c.f = f;
    unsigned int x = c.i;
    unsigned int lsb = (x >> 16) & 1u;
    x += 0x7fffu + lsb;
    return (ushort_t)(x >> 16);
}
__device__ __forceinline__ float sigm(float x) { return 1.f / (1.f + __expf(-x)); }
__device__ __forceinline__ float tanh_f(float x) { return 1.f - 2.f / (__expf(2.f * x) + 1.f); }

#define MFMA16(a, b, c) __builtin_amdgcn_mfma_f32_16x16x32_bf16((a), (b), (c), 0, 0, 0)

// Batched poll sweep (R10-proven, -15%): 8 coalesced 8B words/thread (word k
// at hcur + k*256 + tid), IC path (sc0 sc1), ONE s_waitcnt vmcnt(0) per sweep.
__device__ __forceinline__ void poll8_sweep(const ull_t* b0, const ull_t* b1,
                                            const ull_t* b2, const ull_t* b3,
                                            ull_t* o)
{
    asm volatile(
        "global_load_dwordx2 %0, %8, off sc0 sc1\n\t"
        "global_load_dwordx2 %1, %8, off offset:2048 sc0 sc1\n\t"
        "global_load_dwordx2 %2, %9, off sc0 sc1\n\t"
        "global_load_dwordx2 %3, %9, off offset:2048 sc0 sc1\n\t"
        "global_load_dwordx2 %4, %10, off sc0 sc1\n\t"
        "global_load_dwordx2 %5, %10, off offset:2048 sc0 sc1\n\t"
        "global_load_dwordx2 %6, %11, off sc0 sc1\n\t"
        "global_load_dwordx2 %7, %11, off offset:2048 sc0 sc1\n\t"
        "s_waitcnt vmcnt(0)"
        : "=&v"(o[0]), "=&v"(o[1]), "=&v"(o[2]), "=&v"(o[3]),
          "=&v"(o[4]), "=&v"(o[5]), "=&v"(o[6]), "=&v"(o[7])
        : "v"(b0), "v"(b1), "v"(b2), "v"(b3)
        : "memory");
}

// ---------------- fp32 -> bf16 weight conversion, all 9 matrices in one dispatch ----------------
struct CvtArgs {
    const float* s[9];
    ushort_t* d[9];
    int n[9];
};
__global__ __launch_bounds__(256) void cvt_all(CvtArgs a)
{
    int y = blockIdx.y;
    const float* src = a.s[y];
    ushort_t* dst = a.d[y];
    int n = a.n[y];
    int i = (blockIdx.x * 256 + threadIdx.x) * 4;
    if (i < n) {
        float4 v = *(const float4*)(src + i);
        ushort_t o[4] = { f2bf(v.x), f2bf(v.y), f2bf(v.z), f2bf(v.w) };
        *(uint2*)(dst + i) = *(uint2*)o;
    }
}

// ---------------- embedding gather (fp32 -> bf16) + mask output ----------------
__global__ __launch_bounds__(64) void embed_kernel(
    const int* __restrict__ sent, const float* __restrict__ embed,
    ushort_t* __restrict__ emb, float* __restrict__ mask_out)
{
    int blk = blockIdx.x;             // b*T + t
    int b = blk >> 8, t = blk & 255;
    int s = sent[blk];
    int tid = threadIdx.x;            // 64 threads x 4 elems
    float4 v = *(const float4*)(embed + (size_t)s * Ez + tid * 4);
    ushort_t o[4] = { f2bf(v.x), f2bf(v.y), f2bf(v.z), f2bf(v.w) };
    *(uint2*)(emb + ((size_t)t * Bz + b) * Ez + tid * 4) = *(uint2*)o;
    if (tid == 0) mask_out[blk] = (s != 0) ? 1.0f : 0.0f;
}

// ---------------- input-projection GEMM (R7-proven m97 structure, kept) ----------------
__global__ __launch_bounds__(256) void gemm_xproj(
    const ushort_t* __restrict__ A,                                      // (M, Kd) bf16
    const ushort_t* __restrict__ Wf, const ushort_t* __restrict__ Wb,    // (1024, Kd) bf16
    const float* __restrict__ biasf, const float* __restrict__ biasb,    // (1024,) fp32
    ushort_t* __restrict__ Cf, ushort_t* __restrict__ Cb,                // (M, 1024) bf16
    int M, int Kd)
{
    const ushort_t* W = blockIdx.z ? Wb : Wf;
    const float* bias = blockIdx.z ? biasb : biasf;
    ushort_t* C = blockIdx.z ? Cb : Cf;
    __shared__ __attribute__((aligned(16))) ushort_t sA[128 * 32];   // 8KB, row-major [128][32]
    __shared__ __attribute__((aligned(16))) ushort_t sB[128 * 32];   // 8KB

    int m0 = blockIdx.x * 128, n0 = blockIdx.y * 128;
    int tid = threadIdx.x, l = tid & 63, w = tid >> 6;
    int lr = l & 15, lq = l >> 4;
    int mw = (w & 1) * 64, nw = (w >> 1) * 64;     // wave's 64x64 quadrant

    int srow_lane = l >> 2;
    int scol_lane = (l & 3) * 8;

    f32x4 acc[4][4] = {};
    for (int ko = 0; ko < Kd; ko += 32) {
        #pragma unroll
        for (int j = 0; j < 4; j++) {
            int seg = w * 4 + j;
            const ushort_t* src;
            ushort_t* dst;
            if (seg < 8) {
                src = A + (size_t)(m0 + seg * 16 + srow_lane) * Kd + ko + scol_lane;
                dst = sA + seg * 512;
            } else {
                src = W + (size_t)(n0 + (seg - 8) * 16 + srow_lane) * Kd + ko + scol_lane;
                dst = sB + (seg - 8) * 512;
            }
            __builtin_amdgcn_global_load_lds(src, dst, 16, 0, 0);
        }
        asm volatile("s_waitcnt vmcnt(0)" ::: "memory");
        __syncthreads();

        short8 af[4], bf_[4];
        #pragma unroll
        for (int mt = 0; mt < 4; mt++)
            af[mt] = *(const short8*)(&sA[(mw + mt * 16 + lr) * 32 + lq * 8]);
        #pragma unroll
        for (int nt = 0; nt < 4; nt++)
            bf_[nt] = *(const short8*)(&sB[(nw + nt * 16 + lr) * 32 + lq * 8]);
        #pragma unroll
        for (int mt = 0; mt < 4; mt++)
            #pragma unroll
            for (int nt = 0; nt < 4; nt++)
                acc[mt][nt] = MFMA16(af[mt], bf_[nt], acc[mt][nt]);
        __syncthreads();
    }

    #pragma unroll
    for (int mt = 0; mt < 4; mt++)
        #pragma unroll
        for (int nt = 0; nt < 4; nt++)
            #pragma unroll
            for (int r = 0; r < 4; r++) {
                int row = m0 + mw + mt * 16 + lq * 4 + r;
                int col = n0 + nw + nt * 16 + lr;
                float v = acc[mt][nt][r] + bias[col];
                C[(size_t)row * G4 + col] = f2bf(v);
            }
}

// ---------------- LSTM recurrence, one layer, both dirs ----------------
// R10 EXACT (best measured: 630us/dispatch, total 1661). 32 blocks x 256
// threads, tagged-word protocol, cooperative coalesced poll batched in asm
// (8 loads + one vmcnt(0)/sweep), sH + ONE barrier, AGENT-scope publish.
// SETTLED (R2-R11): the h-exchange lives at the IC; scope bits (R2), XCD
// colocation (R3), L2 sc0 paths (R4/R6), per-frag uncoalesced polls (R5),
// 8x1024 agents (R8), flag/data split (R9), fragment-direct relayout (R11)
// all regress. The batched sweep (R10) is the one proven win (-15%).
#define LDK 264         // 256 + 8 pad (bf16 elems)

__global__ __launch_bounds__(256, 1) void lstm_layer(
    const ushort_t* __restrict__ Whh_f, const ushort_t* __restrict__ Whh_b,  // (1024,256) bf16
    const ushort_t* __restrict__ Xp_f, const ushort_t* __restrict__ Xp_b,    // (T*B, 1024) preact incl bias
    const int* __restrict__ lengths,                                         // (B,)
    ushort_t* __restrict__ hcat,                                             // (T*B, 512)
    ull_t* __restrict__ hbuf)       // [buf(2)][dir(2)][B][H/4] 8B words, pre-zeroed
{
    __shared__ __attribute__((aligned(16))) ushort_t sH[Bz][LDK];
    __shared__ float sG[4][16][34];   // per-wave gates scratch (stride 34: <=2-way)

    int bid = blockIdx.x;
    int dir = bid >> 4;
    int sub = bid & 15;
    int h0 = sub * 16;
    const ushort_t* Whh = dir ? Whh_b : Whh_f;
    const ushort_t* Xp  = dir ? Xp_b  : Xp_f;
    int tid = threadIdx.x, l = tid & 63, w = tid >> 6;
    int lr = l & 15, lq = l >> 4;
    int mw = (w & 1) * 16;       // batch tile
    int P  = w >> 1;             // unit pair
    int U0w = h0 + P * 8;

    // B fragments in registers; col cI=lr -> (unit U0w + (lr>>2), gate lr&3), tile1 = +4 units
    short8 bw0[8], bw1[8];
    int gA = (lr & 3) * Hz + U0w + (lr >> 2);   // Whh row == Xp col, tile 0
    int gB = gA + 4;                             // tile 1
    {
        const ushort_t* W0 = Whh + (size_t)gA * Hz;
        const ushort_t* W1 = Whh + (size_t)gB * Hz;
        #pragma unroll
        for (int k = 0; k < 8; k++) {
            bw0[k] = *(const short8*)(W0 + k * 32 + lq * 8);
            bw1[k] = *(const short8*)(W1 + k * 32 + lq * 8);
        }
    }

    // update lanes: l<32: b_loc = l&15, q = (l>>4)&1 -> units U0w + q*4 .. +4
    int upd = (l < 32);
    int bloc = l & 15;
    int q = (l >> 4) & 1;
    int batch = mw + bloc;
    int lenb = lengths[batch];
    float c4[4] = {0.f, 0.f, 0.f, 0.f};
    ull_t prevw = 0;                               // last published word (untagged)
    int pubw = batch * 64 + sub * 4 + P * 2 + q;   // hbuf word index within buffer
    int hcoff = dir * Hz + U0w + q * 4;            // hcat ushort offset within row

    for (int s = 0; s < Tz; s++) {
        int t_act = dir ? (Tz - 1 - s) : s;
        const ushort_t* Xrow = Xp + (size_t)t_act * Bz * G4;

        // Xp prefetch (independent of h; overlaps the poll)
        float xv0[4], xv1[4];
        #pragma unroll
        for (int r = 0; r < 4; r++) {
            int brow = mw + lq * 4 + r;
            xv0[r] = bf2f(Xrow[(size_t)brow * G4 + gA]);
            xv1[r] = bf2f(Xrow[(size_t)brow * G4 + gB]);
        }

        // ---- batched cooperative poll: one sweep = 8 loads + ONE vmcnt(0) ----
        const ull_t* hcur = hbuf + ((s & 1) * 2 + dir) * (Bz * Hz / 4);
        const ull_t* b0 = hcur + tid;          // k=0,1 (offset 0 / 2048B)
        const ull_t* b1 = b0 + 512;            // k=2,3
        const ull_t* b2 = b0 + 1024;           // k=4,5
        const ull_t* b3 = b0 + 1536;           // k=6,7
        uint_t tagc = (uint_t)(((s >> 1) ^ s) & 1);
        ull_t vals[8];
        for (;;) {
            poll8_sweep(b0, b1, b2, b3, vals);
            uint_t ok = 1u;
            #pragma unroll
            for (int k = 0; k < 8; k++)
                ok &= (((uint_t)(vals[k] >> 14) & 1u) == tagc);
            if (ok) break;
        }
        // write sH only AFTER full detect (overwrite-safety invariant)
        #pragma unroll
        for (int k = 0; k < 8; k++) {
            int idx = k * 256 + tid;
            *(ull_t*)(&sH[idx >> 6][(idx & 63) * 4]) = vals[k] & ~(1ull << 14);
        }
        __syncthreads();   // the ONE barrier per step

        // ---- 16 MFMAs (A from sH, B resident) ----
        f32x4 acc0 = {}, acc1 = {};
        #pragma unroll
        for (int k = 0; k < 8; k++) {
            short8 a = *(const short8*)(&sH[mw + lr][k * 32 + lq * 8]);
            acc0 = MFMA16(a, bw0[k], acc0);
            acc1 = MFMA16(a, bw1[k], acc1);
        }
        // gates + Xp -> per-wave LDS transpose
        #pragma unroll
        for (int r = 0; r < 4; r++) {
            sG[w][lq * 4 + r][lr]      = acc0[r] + xv0[r];
            sG[w][lq * 4 + r][16 + lr] = acc1[r] + xv1[r];
        }
        asm volatile("s_waitcnt lgkmcnt(0)" ::: "memory");   // wave-local ordering

        // ---- cell update + tagged publish (lanes 0..31 of each wave) ----
        uint_t tagp = (uint_t)((((s + 1) >> 1) ^ (s + 1)) & 1);
        if (upd) {
            int msk = (t_act < lenb);
            ushort_t hx[4], hc[4];
            const ushort_t* ho = (const ushort_t*)&prevw;
            #pragma unroll
            for (int j = 0; j < 4; j++) {
                int cb = q * 16 + j * 4;
                float gi = sG[w][bloc][cb], gf = sG[w][bloc][cb + 1];
                float gg = sG[w][bloc][cb + 2], go = sG[w][bloc][cb + 3];
                float c2 = sigm(gf) * c4[j] + sigm(gi) * tanh_f(gg);
                float h2 = sigm(go) * tanh_f(c2);
                if (msk) c4[j] = c2;
                ushort_t hn = f2bf(h2);
                hx[j] = msk ? hn : ho[j];
                hc[j] = msk ? hn : (ushort_t)0;
            }
            ull_t wd; __builtin_memcpy(&wd, hx, 8);
            prevw = wd;
            wd |= ((ull_t)tagp) << 14;
            ull_t* hnxt = hbuf + (((s + 1) & 1) * 2 + dir) * (Bz * Hz / 4);
            __hip_atomic_store(&hnxt[pubw], wd,
                               __ATOMIC_RELAXED, __HIP_MEMORY_SCOPE_AGENT);
            ull_t wc; __builtin_memcpy(&wc, hc, 8);
            *(ull_t*)(hcat + ((size_t)t_act * Bz + batch) * H2 + hcoff) = wc;
        }
    }
}

// ---------------- emit GEMM: (8192,512) @ Wout(48,512)^T + bout -> fp32 out[b][t][k] ----------------
__global__ __launch_bounds__(256) void gemm_emit(
    const ushort_t* __restrict__ A, const ushort_t* __restrict__ Wout,
    const float* __restrict__ bout, float* __restrict__ emit_out)
{
    int tid = threadIdx.x, l = tid & 63, w = tid >> 6;
    int m0 = blockIdx.x * 64 + w * 16;
    int lr = l & 15, lq = l >> 4;
    f32x4 acc[3] = {};
    for (int ko = 0; ko < H2; ko += 32) {
        short8 a = *(const short8*)(A + (size_t)(m0 + lr) * H2 + ko + lq * 8);
        #pragma unroll
        for (int nt = 0; nt < 3; nt++) {
            short8 bfr = *(const short8*)(Wout + (size_t)(nt * 16 + lr) * H2 + ko + lq * 8);
            acc[nt] = MFMA16(a, bfr, acc[nt]);
        }
    }
    #pragma unroll
    for (int nt = 0; nt < 3; nt++)
        #pragma unroll
        for (int r = 0; r < 4; r++) {
            int row = m0 + lq * 4 + r;            // t*B + b
            int col = nt * 16 + lr;
            float v = acc[nt][r] + bout[col];
            int t = row >> 5, b = row & 31;
            emit_out[((size_t)b * Tz + t) * Kz + col] = v;
        }
}

// ---------------- fused CRF numerator + denominator ----------------
// num phase: identical math to the old crf_num (256 threads, shuffle+LDS
// block reduce). den phase: forward algorithm with the 48x48 logsumexp
// PARALLELIZED over 4 waves (wave w sums i in [w*12, w*12+12)); per t:
// redundant per-wave shuffle-max of sS, 12 exp per lane (was 48 on 1 wave),
// LDS partial reduce, wave 0 finalizes. 2 syncthreads/t.
__global__ __launch_bounds__(256) void crf_numden(
    const float* __restrict__ emit, const int* __restrict__ sent,
    const int* __restrict__ tags, const int* __restrict__ lengths,
    const float* __restrict__ trans, const float* __restrict__ start_t,
    const float* __restrict__ end_t, float* __restrict__ num,
    float* __restrict__ den)
{
    __shared__ float red[4];
    __shared__ float sT[Kz * Kz];     // [i*48 + l]
    __shared__ float sS[Kz];
    __shared__ float sP[4][Kz];       // per-wave partials
    int b = blockIdx.x, t = threadIdx.x;
    int w = t >> 6, l = t & 63;
    int len = lengths[b];

    for (int i = t; i < Kz * Kz; i += 256) sT[i] = trans[i];

    // ---- num phase ----
    int tg = tags[b * Tz + t];
    float term;
    if (t == 0) {
        term = start_t[tg] + emit[(size_t)b * Tz * Kz + tg];
        term += end_t[tags[b * Tz + len - 1]];
    } else if (sent[b * Tz + t] != 0) {
        int tp = tags[b * Tz + t - 1];
        term = trans[tp * Kz + tg] + emit[((size_t)b * Tz + t) * Kz + tg];
    } else term = 0.f;
    #pragma unroll
    for (int off = 1; off < 64; off <<= 1) term += __shfl_xor(term, off);
    if (l == 0) red[w] = term;

    // ---- den init ----
    bool act = l < Kz;
    if (w == 0 && act) sS[l] = start_t[l] + emit[(size_t)b * Tz * Kz + l];
    __syncthreads();
    if (t == 0) num[b] = red[0] + red[1] + red[2] + red[3];

    // ---- den forward loop ----
    int i0 = w * 12;
    for (int tt = 1; tt < len; tt++) {
        float sv = act ? sS[l] : -1e30f;
        float M = sv;
        #pragma unroll
        for (int off = 1; off < 64; off <<= 1) M = fmaxf(M, __shfl_xor(M, off));
        float a = 0.f;
        #pragma unroll
        for (int i = 0; i < 12; i++)
            a += __expf(sS[i0 + i] + sT[(i0 + i) * Kz + l] - M);
        if (act) sP[w][l] = a;
        __syncthreads();
        if (w == 0 && act) {
            float sum = (sP[0][l] + sP[1][l]) + (sP[2][l] + sP[3][l]);
            float em = emit[((size_t)b * Tz + tt) * Kz + l];
            sS[l] = em + M + __logf(sum);
        }
        __syncthreads();
    }
    // ---- den final logsumexp ----
    if (w == 0) {
        float v = act ? (sS[l] + end_t[l]) : -1e30f;
        float M = v;
        #pragma unroll
        for (int off = 1; off < 64; off <<= 1) M = fmaxf(M, __shfl_xor(M, off));
        float accv = act ? __expf(v - M) : 0.f;
        #pragma unroll
        for (int off = 1; off < 64; off <<= 1) accv += __shfl_xor(accv, off);
        if (l == 0) den[b] = M + __logf(accv);
    }
}

// ---------------- final loss ----------------
__global__ __launch_bounds__(64) void crf_loss(
    const float* __restrict__ num, const float* __restrict__ den, float* __restrict__ out)
{
    int l = threadIdx.x;
    float v = (l < Bz) ? (num[l] - den[l]) : 0.f;
    #pragma unroll
    for (int off = 1; off < 64; off <<= 1) v += __shfl_xor(v, off);
    if (l == 0) out[0] = v / (float)Bz;
}

extern "C" void kernel_launch(void* const* d_in, const int* in_sizes, int n_in,
                              void* d_out, int out_size, void* d_ws, size_t ws_size,
                              hipStream_t stream) {
    const int* sent      = (const int*)d_in[0];
    const int* lengths   = (const int*)d_in[1];
    const int* tags      = (const int*)d_in[2];
    const float* embed   = (const float*)d_in[3];
    const float* Wih0f = (const float*)d_in[4];
    const float* Whh0f = (const float*)d_in[5];
    const float* b0f   = (const float*)d_in[6];
    const float* Wih0b = (const float*)d_in[7];
    const float* Whh0b = (const float*)d_in[8];
    const float* b0b   = (const float*)d_in[9];
    const float* Wih1f = (const float*)d_in[10];
    const float* Whh1f = (const float*)d_in[11];
    const float* b1f   = (const float*)d_in[12];
    const float* Wih1b = (const float*)d_in[13];
    const float* Whh1b = (const float*)d_in[14];
    const float* b1b   = (const float*)d_in[15];
    const float* Wout  = (const float*)d_in[16];
    const float* bout  = (const float*)d_in[17];
    const float* start_t = (const float*)d_in[18];
    const float* end_t   = (const float*)d_in[19];
    const float* trans   = (const float*)d_in[20];

    char* ws = (char*)d_ws;
    ushort_t* Xp_f  = (ushort_t*)(ws);                        // 16 MB
    ushort_t* Xp_b  = (ushort_t*)(ws + 16777216);             // 16 MB
    ushort_t* hcat  = (ushort_t*)(ws + 33554432);             // 8 MB (layer0 out, then layer1 out)
    ushort_t* emb   = (ushort_t*)(ws + 41943040);             // 4 MB
    ushort_t* Whh0f_c = (ushort_t*)(ws + 46137344);           // 512 KB each
    ushort_t* Whh0b_c = (ushort_t*)(ws + 46661632);
    ushort_t* Wih0f_c = (ushort_t*)(ws + 47185920);
    ushort_t* Wih0b_c = (ushort_t*)(ws + 47710208);
    ushort_t* Wih1f_c = (ushort_t*)(ws + 48234496);           // 1 MB each
    ushort_t* Wih1b_c = (ushort_t*)(ws + 49283072);
    ushort_t* Whh1f_c = (ushort_t*)(ws + 50331648);           // 512 KB each
    ushort_t* Whh1b_c = (ushort_t*)(ws + 50855936);
    ushort_t* Wout_c  = (ushort_t*)(ws + 51380224);           // 48 KB
    ull_t*    hbufL0 = (ull_t*)(ws + 51429376);               // 128 KB: [2][2][B][H/4] 8B words
    ull_t*    hbufL1 = (ull_t*)(ws + 51560448);               // 128 KB
    float*    num   = (float*)   (ws + 51691520);
    float*    den   = (float*)   (ws + 51691776);

    float* out      = (float*)d_out;                          // emit [B][T][K]
    float* loss_out = out + (size_t)Bz * Tz * Kz;             // 393216
    float* mask_out = loss_out + 1;                           // (B,T)

    // zero both layers' h double-buffers (tag protocol: zero word = valid h=0 for step 0)
    hipMemsetAsync(hbufL0, 0, 262144, stream);

    CvtArgs ca;
    ca.s[0] = Whh0f; ca.d[0] = Whh0f_c; ca.n[0] = 262144;
    ca.s[1] = Whh0b; ca.d[1] = Whh0b_c; ca.n[1] = 262144;
    ca.s[2] = Wih0f; ca.d[2] = Wih0f_c; ca.n[2] = 262144;
    ca.s[3] = Wih0b; ca.d[3] = Wih0b_c; ca.n[3] = 262144;
    ca.s[4] = Wih1f; ca.d[4] = Wih1f_c; ca.n[4] = 524288;
    ca.s[5] = Wih1b; ca.d[5] = Wih1b_c; ca.n[5] = 524288;
    ca.s[6] = Whh1f; ca.d[6] = Whh1f_c; ca.n[6] = 262144;
    ca.s[7] = Whh1b; ca.d[7] = Whh1b_c; ca.n[7] = 262144;
    ca.s[8] = Wout;  ca.d[8] = Wout_c;  ca.n[8] = 24576;
    cvt_all<<<dim3(512, 9), 256, 0, stream>>>(ca);

    embed_kernel<<<Bz * Tz, 64, 0, stream>>>(sent, embed, emb, mask_out);

    gemm_xproj<<<dim3(Tz * Bz / 128, G4 / 128, 2), 256, 0, stream>>>(
        emb, Wih0f_c, Wih0b_c, b0f, b0b, Xp_f, Xp_b, Tz * Bz, Ez);

    lstm_layer<<<32, 256, 0, stream>>>(Whh0f_c, Whh0b_c, Xp_f, Xp_b, lengths, hcat, hbufL0);

    gemm_xproj<<<dim3(Tz * Bz / 128, G4 / 128, 2), 256, 0, stream>>>(
        hcat, Wih1f_c, Wih1b_c, b1f, b1b, Xp_f, Xp_b, Tz * Bz, H2);

    lstm_layer<<<32, 256, 0, stream>>>(Whh1f_c, Whh1b_c, Xp_f, Xp_b, lengths, hcat, hbufL1);

    gemm_emit<<<Tz * Bz / 64, 256, 0, stream>>>(hcat, Wout_c, bout, out);

    crf_numden<<<Bz, 256, 0, stream>>>(out, sent, tags, lengths, trans, start_t, end_t, num, den);
    crf_loss<<<1, 64, 0, stream>>>(num, den, loss_out);
}